// Round 13
// baseline (237.667 us; speedup 1.0000x reference)
//
#include <hip/hip_runtime.h>
#include <hip/hip_bf16.h>
#include <stdint.h>

// Problem: B=8192, E=1024, P=512. x:[8192,2048] f32, w:[1024,512] f32, b:[512] f32.
// out: scalar = mean_i( -S[i,i^4096]/T + log(sum_{j!=i} exp(S[i,j]/T)) ),
// S = zn zn^T (symmetric -> upper triangle of 128x128 blocks), T=0.1.
//
// R13 = R10-exact (best measured: 153.6us) with ONE change: gemm2
// __launch_bounds__(256,3) -> (256,6). gemm2 is VGPR=72/LDS=16KB, so by
// resources ~6 blocks/CU fit; the old hint pinned residency at ~2-3. More
// co-resident blocks is the only mechanism that has ever improved these
// stall-dominated 2-barrier loops (R0 3blk/CU vs R3 1blk/CU).
// gemm1qn = R10 verbatim (B-in-regs dbuf; 42-46us floor, 5 structures tried).
//
// ws layout (bytes):
//   wt8 fp8  [512][1024]    @ 0
//   zn4 fp4  [8192][512]    @ 68157440
//   sumexp f32[8192]        @ 84934656
//   pos    f32[8192]        @ 84967424

typedef __attribute__((ext_vector_type(4))) float f32x4;
typedef __attribute__((ext_vector_type(4))) int i32x4;
typedef __attribute__((ext_vector_type(8))) int i32x8;

// e2m1 (OCP FP4) round-to-nearest encode of |v| with sign; codes:
// 0:0 1:0.5 2:1 3:1.5 4:2 5:3 6:4 7:6
__device__ __forceinline__ unsigned int enc4(float v) {
  unsigned int s = (__float_as_uint(v) >> 28) & 8u;
  float a = fabsf(v);
  unsigned int m;
  if (a < 0.25f) m = 0u;
  else if (a < 0.75f) m = 1u;
  else if (a < 1.25f) m = 2u;
  else if (a < 1.75f) m = 3u;
  else if (a < 2.5f)  m = 4u;
  else if (a < 3.5f)  m = 5u;
  else if (a < 5.0f)  m = 6u;
  else m = 7u;
  return s | m;
}

// ---------------- wtr: wt8[n][k] = fp8(64*w[k][n]) via LDS transpose --------
// + zeros sumexp/out.
__global__ __launch_bounds__(256) void wtr_kernel(
    const float* __restrict__ w, unsigned char* __restrict__ wt8,
    float* __restrict__ sumexp, float* __restrict__ out) {
  __shared__ unsigned char lt[64][68];
  int b = blockIdx.x, t = threadIdx.x;
  int gt = b * 256 + t;
  if (gt < 8192) sumexp[gt] = 0.f;
  if (gt == 0) out[0] = 0.f;
  int k0 = (b >> 3) * 64, n0 = (b & 7) * 64;
  int r = t >> 4, c = t & 15;
#pragma unroll
  for (int i = 0; i < 4; ++i) {
    int kl = i * 16 + r;
    float4 v = *(const float4*)&w[(size_t)(k0 + kl) * 512 + n0 + c * 4];
    int q = __builtin_amdgcn_cvt_pk_fp8_f32(v.x * 64.f, v.y * 64.f, 0, false);
    q = __builtin_amdgcn_cvt_pk_fp8_f32(v.z * 64.f, v.w * 64.f, q, true);
    *(int*)&lt[kl][c * 4] = q;
  }
  __syncthreads();
  int nl = t >> 2, ks = t & 3;
  union { unsigned char b8[16]; i32x4 v4; } u;
#pragma unroll
  for (int j = 0; j < 16; ++j) u.b8[j] = lt[ks * 16 + j][nl];
  *(i32x4*)&wt8[(size_t)(n0 + nl) * 1024 + k0 + ks * 16] = u.v4;
}

// -------- gemm1qn: zn4 = fp4(32*normrow(relu(x)@w + b)), B in registers -----
// R10 verbatim. 256 blocks x 512 thr (8 waves). Block = 64 a-rows x 512
// n-cols = 32 zn rows. LDS 16 KB: A dbuf 2x8KB only. A fused: thread
// (ra=tid>>3, kq=tid&7) loads 16 f32, relu*16 -> fp8, ds_write_b128 to slot
// (kq>>1)*2048 + (((ra*2)^((ra>>2)&7))^(kq&1))*16 (involution vs read p0).
// B: per wave w, frag nt: row = w*64+nt*16+l4, register dbuf b0/b1,
// prefetch s+1 issued before MFMA(s). One barrier/step (A dbuf publish).
// A-frag lane L: m=L&15, k=(L>>4)*32+j. C/D: col=L&15, row=(L>>4)*4+reg.
__global__ __launch_bounds__(512) void gemm1qn_kernel(
    const float* __restrict__ x, const unsigned char* __restrict__ wt8,
    const float* __restrict__ bias, unsigned char* __restrict__ zn4) {
  __shared__ unsigned char smem[16384] __attribute__((aligned(16)));
  int i0 = blockIdx.x * 64;
  int tid = threadIdx.x, L = tid & 63, w = tid >> 6;
  int l4 = L & 15, q = L >> 4;

  // ---- fused A-staging decode ----
  int ra = tid >> 3, kq = tid & 7;
  int Aoff = (kq >> 1) * 2048 + ((((ra * 2) ^ ((ra >> 2) & 7)) ^ (kq & 1))) * 16;
  const float* xq = x + (size_t)(i0 + ra) * 1024 + kq * 16;

  auto writeA = [&](int buf, const float4* xv) {
    int pk[4];
#pragma unroll
    for (int j = 0; j < 4; ++j) {
      int p = __builtin_amdgcn_cvt_pk_fp8_f32(fmaxf(xv[j].x, 0.f) * 16.f,
                                              fmaxf(xv[j].y, 0.f) * 16.f, 0, false);
      p = __builtin_amdgcn_cvt_pk_fp8_f32(fmaxf(xv[j].z, 0.f) * 16.f,
                                          fmaxf(xv[j].w, 0.f) * 16.f, p, true);
      pk[j] = p;
    }
    *(i32x4*)(smem + buf * 8192 + Aoff) = (i32x4){pk[0], pk[1], pk[2], pk[3]};
  };

  // ---- A read-side swizzled offsets ----
  int pAo[4];
#pragma unroll
  for (int mt = 0; mt < 4; ++mt) {
    int r = mt * 16 + l4;
    pAo[mt] = ((r * 2) ^ ((r >> 2) & 7)) * 16;
  }

  // ---- B direct global pointers (L2-resident wt8) ----
  const unsigned char* bp[4];
#pragma unroll
  for (int nt = 0; nt < 4; ++nt) {
    int r = w * 64 + nt * 16 + l4;
    bp[nt] = wt8 + (size_t)r * 1024 + q * 32;
  }

  f32x4 acc[4][4];
#pragma unroll
  for (int a = 0; a < 4; ++a)
#pragma unroll
    for (int bq = 0; bq < 4; ++bq) acc[a][bq] = (f32x4)0.f;

  // ---- prologue: A tile 0 + B step 0 ----
  float4 xv[4];
#pragma unroll
  for (int j = 0; j < 4; ++j) xv[j] = *(const float4*)(xq + j * 4);
  writeA(0, xv);
  i32x4 b0[4][2], b1[4][2];
#pragma unroll
  for (int nt = 0; nt < 4; ++nt) {
    b0[nt][0] = *(const i32x4*)(bp[nt]);
    b0[nt][1] = *(const i32x4*)(bp[nt] + 16);
  }
  __syncthreads();

  auto step = [&](int s, i32x4 (&bu)[4][2], i32x4 (&bl)[4][2]) {
    if (s < 7) {
#pragma unroll
      for (int j = 0; j < 4; ++j)
        xv[j] = *(const float4*)(xq + (s + 1) * 128 + j * 4);
#pragma unroll
      for (int nt = 0; nt < 4; ++nt) {
        bl[nt][0] = *(const i32x4*)(bp[nt] + (s + 1) * 128);
        bl[nt][1] = *(const i32x4*)(bp[nt] + (s + 1) * 128 + 16);
      }
    }
    const unsigned char* Ab = smem + (s & 1) * 8192 + q * 2048;
    i32x8 afr[4];
#pragma unroll
    for (int mt = 0; mt < 4; ++mt) {
      i32x4 lo = *(const i32x4*)(Ab + pAo[mt]);
      i32x4 hi = *(const i32x4*)(Ab + (pAo[mt] ^ 16));
      afr[mt] = (i32x8){lo.x, lo.y, lo.z, lo.w, hi.x, hi.y, hi.z, hi.w};
    }
#pragma unroll
    for (int nt = 0; nt < 4; ++nt) {
      i32x8 bfr = (i32x8){bu[nt][0].x, bu[nt][0].y, bu[nt][0].z, bu[nt][0].w,
                          bu[nt][1].x, bu[nt][1].y, bu[nt][1].z, bu[nt][1].w};
#pragma unroll
      for (int mt = 0; mt < 4; ++mt)
        acc[mt][nt] = __builtin_amdgcn_mfma_scale_f32_16x16x128_f8f6f4(
            afr[mt], bfr, acc[mt][nt], 0, 0,
            0, 0x7F7F7F7F, 0, 0x7F7F7F7F);
    }
    if (s < 7) writeA((s + 1) & 1, xv);
    __syncthreads();
  };
  step(0, b0, b1); step(1, b1, b0); step(2, b0, b1); step(3, b1, b0);
  step(4, b0, b1); step(5, b1, b0); step(6, b0, b1); step(7, b1, b0);

  // ---- epilogue: z = acc/1024 + bias; row sumsq; fp4 encode at scale 32 ----
  const float SC = 1.0f / 1024.0f;
  float bn[4];
#pragma unroll
  for (int nt = 0; nt < 4; ++nt) bn[nt] = bias[w * 64 + nt * 16 + l4];
  float ssp[4][4];
#pragma unroll
  for (int mt = 0; mt < 4; ++mt)
#pragma unroll
    for (int r = 0; r < 4; ++r) ssp[mt][r] = 0.f;
#pragma unroll
  for (int mt = 0; mt < 4; ++mt)
#pragma unroll
    for (int nt = 0; nt < 4; ++nt)
#pragma unroll
      for (int r = 0; r < 4; ++r) {
        float zv = acc[mt][nt][r] * SC + bn[nt];
        acc[mt][nt][r] = zv;
        ssp[mt][r] += zv * zv;
      }
#pragma unroll
  for (int mt = 0; mt < 4; ++mt)
#pragma unroll
    for (int r = 0; r < 4; ++r) {
      float v = ssp[mt][r];
      v += __shfl_xor(v, 1); v += __shfl_xor(v, 2);
      v += __shfl_xor(v, 4); v += __shfl_xor(v, 8);
      ssp[mt][r] = v;
    }
  float* ssbuf = (float*)smem;          // [64 rows][8 waves], post-barrier alias
  if (l4 == 0) {
#pragma unroll
    for (int mt = 0; mt < 4; ++mt)
#pragma unroll
      for (int r = 0; r < 4; ++r)
        ssbuf[(mt * 16 + q * 4 + r) * 8 + w] = ssp[mt][r];
  }
  __syncthreads();
  float* invbuf = (float*)(smem + 2048);  // [32 zn rows]
  if (tid < 32) {
    float tot = 0.f;
#pragma unroll
    for (int j = 0; j < 8; ++j)
      tot += ssbuf[(2 * tid) * 8 + j] + ssbuf[(2 * tid + 1) * 8 + j];
    invbuf[tid] = 32.f / fmaxf(sqrtf(tot), 1e-8f);
  }
  __syncthreads();
#pragma unroll
  for (int mt = 0; mt < 4; ++mt)
#pragma unroll
    for (int r = 0; r < 4; ++r) {
      int zr = mt * 16 + q * 4 + r;
      float inv = invbuf[zr >> 1];
      int zg = i0 + zr;
      size_t base = (size_t)(zg >> 1) * 512 + (size_t)(zg & 1) * 256;
#pragma unroll
      for (int nt = 0; nt < 4; ++nt) {
        unsigned int n = enc4(acc[mt][nt][r] * inv);
        unsigned int hi = (unsigned int)__shfl_xor((int)n, 1);
        if (!(l4 & 1)) {
          int col = w * 64 + nt * 16 + l4;
          zn4[base + (col >> 1)] = (unsigned char)(n | (hi << 4));
        }
      }
    }
}

// -------- GEMM2 MXFP4 symmetric: 16x16x128 f8f6f4 cbsz=blgp=4 ----------------
// R10 structure; launch_bounds (256,3) -> (256,6): VGPR=72/LDS=16KB fit
// ~6 blocks/CU; the old hint pinned residency at ~2-3 (Occupancy 24%).
__global__ __launch_bounds__(256, 6) void gemm2_kernel(
    const unsigned char* __restrict__ zn4,
    float* __restrict__ sumexp, float* __restrict__ pos) {
  __shared__ unsigned char As[8192] __attribute__((aligned(16)));
  __shared__ unsigned char Bs[8192] __attribute__((aligned(16)));
  int g = (blockIdx.x & 7) * 260 + (blockIdx.x >> 3);
  int SI = 0, rem = g;
#pragma unroll 1
  for (SI = 0; SI < 8; ++SI) {
    int rowcnt = 36 + (7 - SI) * 64;
    if (rem < rowcnt) break;
    rem -= rowcnt;
  }
  int bi, bj;
  if (rem < 36) {
    int ti = 0;
    while (rem >= 8 - ti) { rem -= 8 - ti; ++ti; }
    bi = SI * 8 + ti;
    bj = bi + rem;
  } else {
    rem -= 36;
    int SJ = SI + 1 + (rem >> 6);
    int l = rem & 63;
    bi = SI * 8 + (l >> 3);
    bj = SJ * 8 + (l & 7);
  }
  bool diag = (bi == bj);
  int i0 = bi * 128, j0 = bj * 128;

  int tid = threadIdx.x, L = tid & 63, w = tid >> 6;
  int wm = w >> 1, wn = w & 1;
  int l4 = L & 15, q = L >> 4;

  int strow = tid >> 2;
  int sq = (tid & 3) ^ ((tid >> 3) & 3);
  const unsigned char* Ag  = zn4 + (size_t)(i0 + strow) * 512 + sq * 16;
  const unsigned char* Ag2 = Ag + 64 * 512;
  const unsigned char* Bg  = zn4 + (size_t)(j0 + strow) * 512 + sq * 16;
  const unsigned char* Bg2 = Bg + 64 * 512;
  int ldb = (tid & ~63) * 16;

  int pA[4], pB[4];
#pragma unroll
  for (int mt = 0; mt < 4; ++mt) {
    int r = wm * 64 + mt * 16 + l4;
    pA[mt] = r * 64 + ((q ^ ((r >> 1) & 3)) << 4);
  }
#pragma unroll
  for (int nt = 0; nt < 4; ++nt) {
    int r = wn * 64 + nt * 16 + l4;
    pB[nt] = r * 64 + ((q ^ ((r >> 1) & 3)) << 4);
  }

  f32x4 acc[4][4];
#pragma unroll
  for (int a = 0; a < 4; ++a)
#pragma unroll
    for (int bq = 0; bq < 4; ++bq) acc[a][bq] = (f32x4)0.f;

  const unsigned char* Bsrc = diag ? (const unsigned char*)As : (const unsigned char*)Bs;

#pragma unroll 1
  for (int koff = 0; koff < 512; koff += 64) {
    __syncthreads();
    __builtin_amdgcn_global_load_lds(
        (const __attribute__((address_space(1))) void*)(Ag + koff),
        (__attribute__((address_space(3))) void*)(As + ldb), 16, 0, 0);
    __builtin_amdgcn_global_load_lds(
        (const __attribute__((address_space(1))) void*)(Ag2 + koff),
        (__attribute__((address_space(3))) void*)(As + 4096 + ldb), 16, 0, 0);
    if (!diag) {
      __builtin_amdgcn_global_load_lds(
          (const __attribute__((address_space(1))) void*)(Bg + koff),
          (__attribute__((address_space(3))) void*)(Bs + ldb), 16, 0, 0);
      __builtin_amdgcn_global_load_lds(
          (const __attribute__((address_space(1))) void*)(Bg2 + koff),
          (__attribute__((address_space(3))) void*)(Bs + 4096 + ldb), 16, 0, 0);
    }
    __syncthreads();
    i32x4 a4[4];
#pragma unroll
    for (int mt = 0; mt < 4; ++mt) a4[mt] = *(const i32x4*)(As + pA[mt]);
#pragma unroll
    for (int nt = 0; nt < 4; ++nt) {
      i32x4 b4 = *(const i32x4*)(Bsrc + pB[nt]);
      i32x8 bfr = (i32x8){b4.x, b4.y, b4.z, b4.w, b4.x, b4.y, b4.z, b4.w};
#pragma unroll
      for (int mt = 0; mt < 4; ++mt) {
        i32x8 afr = (i32x8){a4[mt].x, a4[mt].y, a4[mt].z, a4[mt].w,
                            a4[mt].x, a4[mt].y, a4[mt].z, a4[mt].w};
        acc[mt][nt] = __builtin_amdgcn_mfma_scale_f32_16x16x128_f8f6f4(
            afr, bfr, acc[mt][nt], 4, 4,
            0, 0x7F7F7F7F, 0, 0x7F7F7F7F);
      }
    }
  }

  const float SC = 10.0f / 1024.0f;
  float rs[4][4];
  float cs[4] = {0.f, 0.f, 0.f, 0.f};
#pragma unroll
  for (int mt = 0; mt < 4; ++mt)
#pragma unroll
    for (int r = 0; r < 4; ++r) rs[mt][r] = 0.f;
  int ib = i0 + wm * 64 + (q << 2);
  int jb = j0 + wn * 64 + l4;
#pragma unroll
  for (int mt = 0; mt < 4; ++mt)
#pragma unroll
    for (int nt = 0; nt < 4; ++nt) {
      int j = jb + nt * 16;
#pragma unroll
      for (int r = 0; r < 4; ++r) {
        int i = ib + mt * 16 + r;
        float s = acc[mt][nt][r] * SC;
        if (j == (i ^ 4096)) { pos[i] = s; pos[j] = s; }
        float e = (i == j) ? 0.f : __expf(s);
        rs[mt][r] += e;
        if (!diag) cs[nt] += e;
      }
    }
#pragma unroll
  for (int mt = 0; mt < 4; ++mt)
#pragma unroll
    for (int r = 0; r < 4; ++r) {
      float v = rs[mt][r];
      v += __shfl_xor(v, 1); v += __shfl_xor(v, 2);
      v += __shfl_xor(v, 4); v += __shfl_xor(v, 8);
      rs[mt][r] = v;
    }
  int sel = l4;
  float myv = rs[0][0];
#pragma unroll
  for (int mt = 0; mt < 4; ++mt)
#pragma unroll
    for (int r = 0; r < 4; ++r)
      if (sel == mt * 4 + r) myv = rs[mt][r];
  int rowi = i0 + wm * 64 + (sel >> 2) * 16 + (q << 2) + (sel & 3);
  atomicAdd(&sumexp[rowi], myv);
  if (!diag) {
#pragma unroll
    for (int nt = 0; nt < 4; ++nt) {
      float v = cs[nt];
      v += __shfl_xor(v, 16); v += __shfl_xor(v, 32);
      if (q == 0) atomicAdd(&sumexp[jb + nt * 16], v);
    }
  }
}

// -------- finalize: out += mean-partial(log(sumexp) - pos), 16 blocks --------
__global__ __launch_bounds__(512) void finalize_kernel(
    const float* __restrict__ sumexp, const float* __restrict__ pos,
    float* __restrict__ out) {
  int t = threadIdx.x;
  int i = blockIdx.x * 512 + t;
  float s = logf(sumexp[i]) - pos[i];
#pragma unroll
  for (int off = 1; off < 64; off <<= 1) s += __shfl_xor(s, off);
  __shared__ float red[8];
  if ((t & 63) == 0) red[t >> 6] = s;
  __syncthreads();
  if (t == 0) {
    float tot = 0.f;
    for (int k2 = 0; k2 < 8; ++k2) tot += red[k2];
    atomicAdd(out, tot * (1.0f / 8192.0f));
  }
}

extern "C" void kernel_launch(void* const* d_in, const int* in_sizes, int n_in,
                              void* d_out, int out_size, void* d_ws, size_t ws_size,
                              hipStream_t stream) {
  const float* x = (const float*)d_in[0];
  const float* w = (const float*)d_in[1];
  const float* b = (const float*)d_in[2];
  float* out = (float*)d_out;
  char* ws = (char*)d_ws;
  unsigned char* wt8 = (unsigned char*)(ws);
  unsigned char* zn4 = (unsigned char*)(ws + 68157440);
  float* sumexp      = (float*)(ws + 84934656);
  float* pos         = (float*)(ws + 84967424);

  wtr_kernel<<<128, 256, 0, stream>>>(w, wt8, sumexp, out);
  gemm1qn_kernel<<<256, 512, 0, stream>>>(x, wt8, b, zn4);
  gemm2_kernel<<<2080, 256, 0, stream>>>(zn4, sumexp, pos);
  finalize_kernel<<<16, 512, 0, stream>>>(sumexp, pos, out);
}

// Round 15
// 153.270 us; speedup vs baseline: 1.5506x; 1.5506x over previous
//
#include <hip/hip_runtime.h>
#include <hip/hip_bf16.h>
#include <stdint.h>

// Problem: B=8192, E=1024, P=512. x:[8192,2048] f32, w:[1024,512] f32, b:[512] f32.
// out: scalar = mean_i( -S[i,i^4096]/T + log(sum_{j!=i} exp(S[i,j]/T)) ),
// S = zn zn^T (symmetric -> upper triangle of 128x128 blocks), T=0.1.
//
// R15 == R14 resubmission (container infra failure, no kernel verdict) ==
// R10 byte-exact (best measured: 153.6us, passed, absmax 0.0).
// Ledger: 7 schedule experiments on the GEMMs (dbuf, 8-phase x2, fat-wave,
// single-buf, rotation+raw-barrier, small-tile, occupancy-hint) all null or
// negative vs these simple structures. Remaining time is: harness fill 41us
// (fixed), gemm1qn ~42.5us, gemm2 ~35us, fixed overhead ~30us.
//
// ws layout (bytes):
//   wt8 fp8  [512][1024]    @ 0
//   zn4 fp4  [8192][512]    @ 68157440
//   sumexp f32[8192]        @ 84934656
//   pos    f32[8192]        @ 84967424

typedef __attribute__((ext_vector_type(4))) float f32x4;
typedef __attribute__((ext_vector_type(4))) int i32x4;
typedef __attribute__((ext_vector_type(8))) int i32x8;

// e2m1 (OCP FP4) round-to-nearest encode of |v| with sign; codes:
// 0:0 1:0.5 2:1 3:1.5 4:2 5:3 6:4 7:6
__device__ __forceinline__ unsigned int enc4(float v) {
  unsigned int s = (__float_as_uint(v) >> 28) & 8u;
  float a = fabsf(v);
  unsigned int m;
  if (a < 0.25f) m = 0u;
  else if (a < 0.75f) m = 1u;
  else if (a < 1.25f) m = 2u;
  else if (a < 1.75f) m = 3u;
  else if (a < 2.5f)  m = 4u;
  else if (a < 3.5f)  m = 5u;
  else if (a < 5.0f)  m = 6u;
  else m = 7u;
  return s | m;
}

// ---------------- wtr: wt8[n][k] = fp8(64*w[k][n]) via LDS transpose --------
// + zeros sumexp/out.
__global__ __launch_bounds__(256) void wtr_kernel(
    const float* __restrict__ w, unsigned char* __restrict__ wt8,
    float* __restrict__ sumexp, float* __restrict__ out) {
  __shared__ unsigned char lt[64][68];
  int b = blockIdx.x, t = threadIdx.x;
  int gt = b * 256 + t;
  if (gt < 8192) sumexp[gt] = 0.f;
  if (gt == 0) out[0] = 0.f;
  int k0 = (b >> 3) * 64, n0 = (b & 7) * 64;
  int r = t >> 4, c = t & 15;
#pragma unroll
  for (int i = 0; i < 4; ++i) {
    int kl = i * 16 + r;
    float4 v = *(const float4*)&w[(size_t)(k0 + kl) * 512 + n0 + c * 4];
    int q = __builtin_amdgcn_cvt_pk_fp8_f32(v.x * 64.f, v.y * 64.f, 0, false);
    q = __builtin_amdgcn_cvt_pk_fp8_f32(v.z * 64.f, v.w * 64.f, q, true);
    *(int*)&lt[kl][c * 4] = q;
  }
  __syncthreads();
  int nl = t >> 2, ks = t & 3;
  union { unsigned char b8[16]; i32x4 v4; } u;
#pragma unroll
  for (int j = 0; j < 16; ++j) u.b8[j] = lt[ks * 16 + j][nl];
  *(i32x4*)&wt8[(size_t)(n0 + nl) * 1024 + k0 + ks * 16] = u.v4;
}

// -------- gemm1qn: zn4 = fp4(32*normrow(relu(x)@w + b)), B in registers -----
// R10 verbatim. 256 blocks x 512 thr (8 waves). Block = 64 a-rows x 512
// n-cols = 32 zn rows. LDS 16 KB: A dbuf 2x8KB only. A fused: thread
// (ra=tid>>3, kq=tid&7) loads 16 f32, relu*16 -> fp8, ds_write_b128 to slot
// (kq>>1)*2048 + (((ra*2)^((ra>>2)&7))^(kq&1))*16 (involution vs read p0).
// B: per wave w, frag nt: row = w*64+nt*16+l4, register dbuf b0/b1,
// prefetch s+1 issued before MFMA(s). One barrier/step (A dbuf publish).
// A-frag lane L: m=L&15, k=(L>>4)*32+j. C/D: col=L&15, row=(L>>4)*4+reg.
__global__ __launch_bounds__(512) void gemm1qn_kernel(
    const float* __restrict__ x, const unsigned char* __restrict__ wt8,
    const float* __restrict__ bias, unsigned char* __restrict__ zn4) {
  __shared__ unsigned char smem[16384] __attribute__((aligned(16)));
  int i0 = blockIdx.x * 64;
  int tid = threadIdx.x, L = tid & 63, w = tid >> 6;
  int l4 = L & 15, q = L >> 4;

  // ---- fused A-staging decode ----
  int ra = tid >> 3, kq = tid & 7;
  int Aoff = (kq >> 1) * 2048 + ((((ra * 2) ^ ((ra >> 2) & 7)) ^ (kq & 1))) * 16;
  const float* xq = x + (size_t)(i0 + ra) * 1024 + kq * 16;

  auto writeA = [&](int buf, const float4* xv) {
    int pk[4];
#pragma unroll
    for (int j = 0; j < 4; ++j) {
      int p = __builtin_amdgcn_cvt_pk_fp8_f32(fmaxf(xv[j].x, 0.f) * 16.f,
                                              fmaxf(xv[j].y, 0.f) * 16.f, 0, false);
      p = __builtin_amdgcn_cvt_pk_fp8_f32(fmaxf(xv[j].z, 0.f) * 16.f,
                                          fmaxf(xv[j].w, 0.f) * 16.f, p, true);
      pk[j] = p;
    }
    *(i32x4*)(smem + buf * 8192 + Aoff) = (i32x4){pk[0], pk[1], pk[2], pk[3]};
  };

  // ---- A read-side swizzled offsets ----
  int pAo[4];
#pragma unroll
  for (int mt = 0; mt < 4; ++mt) {
    int r = mt * 16 + l4;
    pAo[mt] = ((r * 2) ^ ((r >> 2) & 7)) * 16;
  }

  // ---- B direct global pointers (L2-resident wt8) ----
  const unsigned char* bp[4];
#pragma unroll
  for (int nt = 0; nt < 4; ++nt) {
    int r = w * 64 + nt * 16 + l4;
    bp[nt] = wt8 + (size_t)r * 1024 + q * 32;
  }

  f32x4 acc[4][4];
#pragma unroll
  for (int a = 0; a < 4; ++a)
#pragma unroll
    for (int bq = 0; bq < 4; ++bq) acc[a][bq] = (f32x4)0.f;

  // ---- prologue: A tile 0 + B step 0 ----
  float4 xv[4];
#pragma unroll
  for (int j = 0; j < 4; ++j) xv[j] = *(const float4*)(xq + j * 4);
  writeA(0, xv);
  i32x4 b0[4][2], b1[4][2];
#pragma unroll
  for (int nt = 0; nt < 4; ++nt) {
    b0[nt][0] = *(const i32x4*)(bp[nt]);
    b0[nt][1] = *(const i32x4*)(bp[nt] + 16);
  }
  __syncthreads();

  auto step = [&](int s, i32x4 (&bu)[4][2], i32x4 (&bl)[4][2]) {
    if (s < 7) {
#pragma unroll
      for (int j = 0; j < 4; ++j)
        xv[j] = *(const float4*)(xq + (s + 1) * 128 + j * 4);
#pragma unroll
      for (int nt = 0; nt < 4; ++nt) {
        bl[nt][0] = *(const i32x4*)(bp[nt] + (s + 1) * 128);
        bl[nt][1] = *(const i32x4*)(bp[nt] + (s + 1) * 128 + 16);
      }
    }
    const unsigned char* Ab = smem + (s & 1) * 8192 + q * 2048;
    i32x8 afr[4];
#pragma unroll
    for (int mt = 0; mt < 4; ++mt) {
      i32x4 lo = *(const i32x4*)(Ab + pAo[mt]);
      i32x4 hi = *(const i32x4*)(Ab + (pAo[mt] ^ 16));
      afr[mt] = (i32x8){lo.x, lo.y, lo.z, lo.w, hi.x, hi.y, hi.z, hi.w};
    }
#pragma unroll
    for (int nt = 0; nt < 4; ++nt) {
      i32x8 bfr = (i32x8){bu[nt][0].x, bu[nt][0].y, bu[nt][0].z, bu[nt][0].w,
                          bu[nt][1].x, bu[nt][1].y, bu[nt][1].z, bu[nt][1].w};
#pragma unroll
      for (int mt = 0; mt < 4; ++mt)
        acc[mt][nt] = __builtin_amdgcn_mfma_scale_f32_16x16x128_f8f6f4(
            afr[mt], bfr, acc[mt][nt], 0, 0,
            0, 0x7F7F7F7F, 0, 0x7F7F7F7F);
    }
    if (s < 7) writeA((s + 1) & 1, xv);
    __syncthreads();
  };
  step(0, b0, b1); step(1, b1, b0); step(2, b0, b1); step(3, b1, b0);
  step(4, b0, b1); step(5, b1, b0); step(6, b0, b1); step(7, b1, b0);

  // ---- epilogue: z = acc/1024 + bias; row sumsq; fp4 encode at scale 32 ----
  const float SC = 1.0f / 1024.0f;
  float bn[4];
#pragma unroll
  for (int nt = 0; nt < 4; ++nt) bn[nt] = bias[w * 64 + nt * 16 + l4];
  float ssp[4][4];
#pragma unroll
  for (int mt = 0; mt < 4; ++mt)
#pragma unroll
    for (int r = 0; r < 4; ++r) ssp[mt][r] = 0.f;
#pragma unroll
  for (int mt = 0; mt < 4; ++mt)
#pragma unroll
    for (int nt = 0; nt < 4; ++nt)
#pragma unroll
      for (int r = 0; r < 4; ++r) {
        float zv = acc[mt][nt][r] * SC + bn[nt];
        acc[mt][nt][r] = zv;
        ssp[mt][r] += zv * zv;
      }
#pragma unroll
  for (int mt = 0; mt < 4; ++mt)
#pragma unroll
    for (int r = 0; r < 4; ++r) {
      float v = ssp[mt][r];
      v += __shfl_xor(v, 1); v += __shfl_xor(v, 2);
      v += __shfl_xor(v, 4); v += __shfl_xor(v, 8);
      ssp[mt][r] = v;
    }
  float* ssbuf = (float*)smem;          // [64 rows][8 waves], post-barrier alias
  if (l4 == 0) {
#pragma unroll
    for (int mt = 0; mt < 4; ++mt)
#pragma unroll
      for (int r = 0; r < 4; ++r)
        ssbuf[(mt * 16 + q * 4 + r) * 8 + w] = ssp[mt][r];
  }
  __syncthreads();
  float* invbuf = (float*)(smem + 2048);  // [32 zn rows]
  if (tid < 32) {
    float tot = 0.f;
#pragma unroll
    for (int j = 0; j < 8; ++j)
      tot += ssbuf[(2 * tid) * 8 + j] + ssbuf[(2 * tid + 1) * 8 + j];
    invbuf[tid] = 32.f / fmaxf(sqrtf(tot), 1e-8f);
  }
  __syncthreads();
#pragma unroll
  for (int mt = 0; mt < 4; ++mt)
#pragma unroll
    for (int r = 0; r < 4; ++r) {
      int zr = mt * 16 + q * 4 + r;
      float inv = invbuf[zr >> 1];
      int zg = i0 + zr;
      size_t base = (size_t)(zg >> 1) * 512 + (size_t)(zg & 1) * 256;
#pragma unroll
      for (int nt = 0; nt < 4; ++nt) {
        unsigned int n = enc4(acc[mt][nt][r] * inv);
        unsigned int hi = (unsigned int)__shfl_xor((int)n, 1);
        if (!(l4 & 1)) {
          int col = w * 64 + nt * 16 + l4;
          zn4[base + (col >> 1)] = (unsigned char)(n | (hi << 4));
        }
      }
    }
}

// -------- GEMM2 MXFP4 symmetric: 16x16x128 f8f6f4 cbsz=blgp=4 (R10 exact) ----
__global__ __launch_bounds__(256, 3) void gemm2_kernel(
    const unsigned char* __restrict__ zn4,
    float* __restrict__ sumexp, float* __restrict__ pos) {
  __shared__ unsigned char As[8192] __attribute__((aligned(16)));
  __shared__ unsigned char Bs[8192] __attribute__((aligned(16)));
  int g = (blockIdx.x & 7) * 260 + (blockIdx.x >> 3);
  int SI = 0, rem = g;
#pragma unroll 1
  for (SI = 0; SI < 8; ++SI) {
    int rowcnt = 36 + (7 - SI) * 64;
    if (rem < rowcnt) break;
    rem -= rowcnt;
  }
  int bi, bj;
  if (rem < 36) {
    int ti = 0;
    while (rem >= 8 - ti) { rem -= 8 - ti; ++ti; }
    bi = SI * 8 + ti;
    bj = bi + rem;
  } else {
    rem -= 36;
    int SJ = SI + 1 + (rem >> 6);
    int l = rem & 63;
    bi = SI * 8 + (l >> 3);
    bj = SJ * 8 + (l & 7);
  }
  bool diag = (bi == bj);
  int i0 = bi * 128, j0 = bj * 128;

  int tid = threadIdx.x, L = tid & 63, w = tid >> 6;
  int wm = w >> 1, wn = w & 1;
  int l4 = L & 15, q = L >> 4;

  int strow = tid >> 2;
  int sq = (tid & 3) ^ ((tid >> 3) & 3);
  const unsigned char* Ag  = zn4 + (size_t)(i0 + strow) * 512 + sq * 16;
  const unsigned char* Ag2 = Ag + 64 * 512;
  const unsigned char* Bg  = zn4 + (size_t)(j0 + strow) * 512 + sq * 16;
  const unsigned char* Bg2 = Bg + 64 * 512;
  int ldb = (tid & ~63) * 16;

  int pA[4], pB[4];
#pragma unroll
  for (int mt = 0; mt < 4; ++mt) {
    int r = wm * 64 + mt * 16 + l4;
    pA[mt] = r * 64 + ((q ^ ((r >> 1) & 3)) << 4);
  }
#pragma unroll
  for (int nt = 0; nt < 4; ++nt) {
    int r = wn * 64 + nt * 16 + l4;
    pB[nt] = r * 64 + ((q ^ ((r >> 1) & 3)) << 4);
  }

  f32x4 acc[4][4];
#pragma unroll
  for (int a = 0; a < 4; ++a)
#pragma unroll
    for (int bq = 0; bq < 4; ++bq) acc[a][bq] = (f32x4)0.f;

  const unsigned char* Bsrc = diag ? (const unsigned char*)As : (const unsigned char*)Bs;

#pragma unroll 1
  for (int koff = 0; koff < 512; koff += 64) {
    __syncthreads();
    __builtin_amdgcn_global_load_lds(
        (const __attribute__((address_space(1))) void*)(Ag + koff),
        (__attribute__((address_space(3))) void*)(As + ldb), 16, 0, 0);
    __builtin_amdgcn_global_load_lds(
        (const __attribute__((address_space(1))) void*)(Ag2 + koff),
        (__attribute__((address_space(3))) void*)(As + 4096 + ldb), 16, 0, 0);
    if (!diag) {
      __builtin_amdgcn_global_load_lds(
          (const __attribute__((address_space(1))) void*)(Bg + koff),
          (__attribute__((address_space(3))) void*)(Bs + ldb), 16, 0, 0);
      __builtin_amdgcn_global_load_lds(
          (const __attribute__((address_space(1))) void*)(Bg2 + koff),
          (__attribute__((address_space(3))) void*)(Bs + 4096 + ldb), 16, 0, 0);
    }
    __syncthreads();
    i32x4 a4[4];
#pragma unroll
    for (int mt = 0; mt < 4; ++mt) a4[mt] = *(const i32x4*)(As + pA[mt]);
#pragma unroll
    for (int nt = 0; nt < 4; ++nt) {
      i32x4 b4 = *(const i32x4*)(Bsrc + pB[nt]);
      i32x8 bfr = (i32x8){b4.x, b4.y, b4.z, b4.w, b4.x, b4.y, b4.z, b4.w};
#pragma unroll
      for (int mt = 0; mt < 4; ++mt) {
        i32x8 afr = (i32x8){a4[mt].x, a4[mt].y, a4[mt].z, a4[mt].w,
                            a4[mt].x, a4[mt].y, a4[mt].z, a4[mt].w};
        acc[mt][nt] = __builtin_amdgcn_mfma_scale_f32_16x16x128_f8f6f4(
            afr, bfr, acc[mt][nt], 4, 4,
            0, 0x7F7F7F7F, 0, 0x7F7F7F7F);
      }
    }
  }

  const float SC = 10.0f / 1024.0f;
  float rs[4][4];
  float cs[4] = {0.f, 0.f, 0.f, 0.f};
#pragma unroll
  for (int mt = 0; mt < 4; ++mt)
#pragma unroll
    for (int r = 0; r < 4; ++r) rs[mt][r] = 0.f;
  int ib = i0 + wm * 64 + (q << 2);
  int jb = j0 + wn * 64 + l4;
#pragma unroll
  for (int mt = 0; mt < 4; ++mt)
#pragma unroll
    for (int nt = 0; nt < 4; ++nt) {
      int j = jb + nt * 16;
#pragma unroll
      for (int r = 0; r < 4; ++r) {
        int i = ib + mt * 16 + r;
        float s = acc[mt][nt][r] * SC;
        if (j == (i ^ 4096)) { pos[i] = s; pos[j] = s; }
        float e = (i == j) ? 0.f : __expf(s);
        rs[mt][r] += e;
        if (!diag) cs[nt] += e;
      }
    }
#pragma unroll
  for (int mt = 0; mt < 4; ++mt)
#pragma unroll
    for (int r = 0; r < 4; ++r) {
      float v = rs[mt][r];
      v += __shfl_xor(v, 1); v += __shfl_xor(v, 2);
      v += __shfl_xor(v, 4); v += __shfl_xor(v, 8);
      rs[mt][r] = v;
    }
  int sel = l4;
  float myv = rs[0][0];
#pragma unroll
  for (int mt = 0; mt < 4; ++mt)
#pragma unroll
    for (int r = 0; r < 4; ++r)
      if (sel == mt * 4 + r) myv = rs[mt][r];
  int rowi = i0 + wm * 64 + (sel >> 2) * 16 + (q << 2) + (sel & 3);
  atomicAdd(&sumexp[rowi], myv);
  if (!diag) {
#pragma unroll
    for (int nt = 0; nt < 4; ++nt) {
      float v = cs[nt];
      v += __shfl_xor(v, 16); v += __shfl_xor(v, 32);
      if (q == 0) atomicAdd(&sumexp[jb + nt * 16], v);
    }
  }
}

// -------- finalize: out += mean-partial(log(sumexp) - pos), 16 blocks --------
__global__ __launch_bounds__(512) void finalize_kernel(
    const float* __restrict__ sumexp, const float* __restrict__ pos,
    float* __restrict__ out) {
  int t = threadIdx.x;
  int i = blockIdx.x * 512 + t;
  float s = logf(sumexp[i]) - pos[i];
#pragma unroll
  for (int off = 1; off < 64; off <<= 1) s += __shfl_xor(s, off);
  __shared__ float red[8];
  if ((t & 63) == 0) red[t >> 6] = s;
  __syncthreads();
  if (t == 0) {
    float tot = 0.f;
    for (int k2 = 0; k2 < 8; ++k2) tot += red[k2];
    atomicAdd(out, tot * (1.0f / 8192.0f));
  }
}

extern "C" void kernel_launch(void* const* d_in, const int* in_sizes, int n_in,
                              void* d_out, int out_size, void* d_ws, size_t ws_size,
                              hipStream_t stream) {
  const float* x = (const float*)d_in[0];
  const float* w = (const float*)d_in[1];
  const float* b = (const float*)d_in[2];
  float* out = (float*)d_out;
  char* ws = (char*)d_ws;
  unsigned char* wt8 = (unsigned char*)(ws);
  unsigned char* zn4 = (unsigned char*)(ws + 68157440);
  float* sumexp      = (float*)(ws + 84934656);
  float* pos         = (float*)(ws + 84967424);

  wtr_kernel<<<128, 256, 0, stream>>>(w, wt8, sumexp, out);
  gemm1qn_kernel<<<256, 512, 0, stream>>>(x, wt8, b, zn4);
  gemm2_kernel<<<2080, 256, 0, stream>>>(zn4, sumexp, pos);
  finalize_kernel<<<16, 512, 0, stream>>>(sumexp, pos, out);
}